// Round 1
// baseline (634.792 us; speedup 1.0000x reference)
//
#include <hip/hip_runtime.h>
#include <math.h>

// Problem constants (match reference file)
#define NN 8000
#define EE 96000
#define HH 4
#define NBASIS 256
#define ECH 48
#define FFNH 128
#define CUTOFF_R 0.0792f
#define PI_F 3.14159265358979323846f
#define SPACING (CUTOFF_R/255.0f)
#define INV_STD (256.0f/CUTOFF_R)
#define MAXDEG 96
#define W1S 52   // padded LDS stride for W1 rows (52*4=208B, 16B aligned, bank-spread)

__device__ __forceinline__ float silu_f(float x){ return x/(1.0f+expf(-x)); }

// ---------- fused weights: wsv = W_src@W_v, wdv = W_dst@W_v  (grid 32x256) ----------
__global__ void k_fusew(const float* __restrict__ Wsrc, const float* __restrict__ Wdst,
                        const float* __restrict__ Wv,
                        float* __restrict__ wsv, float* __restrict__ wdv){
  int gid = blockIdx.x*256 + threadIdx.x;
  int which = gid >> 12;
  int idx = gid & 4095;
  int r = idx >> 6, c = idx & 63;
  const float* A = which ? Wdst : Wsrc;
  float acc = 0.0f;
  #pragma unroll
  for (int k=0;k<64;k++) acc += A[r*64+k]*Wv[k*64+c];
  (which ? wdv : wsv)[idx] = acc;
}

// ---------- rms scale per node (grid NN x 256) ----------
__global__ void __launch_bounds__(256) k_rms(const float* __restrict__ x, float* __restrict__ rms1){
  int n = blockIdx.x;
  float4 v = ((const float4*)(x + (size_t)n*1024))[threadIdx.x];
  float ss = v.x*v.x+v.y*v.y+v.z*v.z+v.w*v.w;
  #pragma unroll
  for (int m=32;m>=1;m>>=1) ss += __shfl_xor(ss, m);
  __shared__ float red[4];
  if ((threadIdx.x & 63)==0) red[threadIdx.x>>6]=ss;
  __syncthreads();
  if (threadIdx.x==0)
    rms1[n] = 1.0f/sqrtf((red[0]+red[1]+red[2]+red[3])*(1.0f/1024.0f)+1e-6f);
}

// ---------- xs0[n,c], xd0[n,c] : l=0 row through W_src/W_dst (grid 2000x256) ----------
__global__ void __launch_bounds__(256) k_node0(const float* __restrict__ x, const float* __restrict__ rms1,
                        const float* __restrict__ Wsrc, const float* __restrict__ Wdst,
                        float* __restrict__ xs0, float* __restrict__ xd0){
  int t = blockIdx.x*256 + threadIdx.x;
  int n = t>>6, c = t&63;
  float sc = rms1[n];
  const float* xr = x + (size_t)n*1024;   // l = 0 row
  float as=0.0f, ad=0.0f;
  #pragma unroll 8
  for (int k=0;k<64;k++){
    float xv = xr[k]*sc;
    as += xv*Wsrc[k*64+c];
    ad += xv*Wdst[k*64+c];
  }
  xs0[t]=as; xd0[t]=ad;
}

// ---------- vs = xn@wsv, vd = xn@wdv over all rows N*L (grid 2000x256, 64 rows/block) ----------
__global__ void __launch_bounds__(256) k_node1(const float* __restrict__ x, const float* __restrict__ rms1,
                        const float* __restrict__ wsv, const float* __restrict__ wdv,
                        float* __restrict__ vs, float* __restrict__ vd){
  __shared__ float xt[64*65];
  __shared__ float wa[4096];
  __shared__ float wb[4096];
  int base = blockIdx.x*64;
  for (int i=threadIdx.x;i<4096;i+=256){
    int r = i>>6, k = i&63;
    int row = base + r;
    xt[r*65+k] = x[(size_t)row*64+k]*rms1[row>>4];
    wa[i] = wsv[i]; wb[i] = wdv[i];
  }
  __syncthreads();
  int r = threadIdx.x>>2, cg = threadIdx.x&3;
  float as[16], ad[16];
  #pragma unroll
  for (int j=0;j<16;j++){ as[j]=0.0f; ad[j]=0.0f; }
  for (int k=0;k<64;k++){
    float a = xt[r*65+k];
    const float* w1p = &wa[k*64+cg*16];
    const float* w2p = &wb[k*64+cg*16];
    #pragma unroll
    for (int j=0;j<16;j++){ as[j] += a*w1p[j]; ad[j] += a*w2p[j]; }
  }
  int row = base + r;
  float* vsp = vs + (size_t)row*64 + cg*16;
  float* vdp = vd + (size_t)row*64 + cg*16;
  #pragma unroll
  for (int j=0;j<16;j++){ vsp[j]=as[j]; vdp[j]=ad[j]; }
}

// ---------- edge RBF + 2-layer MLP -> e2[E,48] (grid 375x256) ----------
__global__ void __launch_bounds__(256) k_edgeA(const float* __restrict__ pos, const int* __restrict__ ei,
                        const float* __restrict__ W1, const float* __restrict__ b1,
                        const float* __restrict__ W2, const float* __restrict__ b2,
                        float* __restrict__ e2g){
  __shared__ float w1[NBASIS*W1S];
  __shared__ float w2[ECH*ECH];
  __shared__ float b1l[ECH], b2l[ECH];
  for (int i=threadIdx.x;i<NBASIS*ECH;i+=256){ int k=i/ECH, j=i-k*ECH; w1[k*W1S+j]=W1[i]; }
  for (int i=threadIdx.x;i<ECH*ECH;i+=256) w2[i]=W2[i];
  if (threadIdx.x<ECH){ b1l[threadIdx.x]=b1[threadIdx.x]; b2l[threadIdx.x]=b2[threadIdx.x]; }
  __syncthreads();
  int e = blockIdx.x*256 + threadIdx.x;   // grid exactly covers EE
  int s = ei[e], t = ei[EE+e];
  float dx = pos[3*s]-pos[3*t], dy = pos[3*s+1]-pos[3*t+1], dz = pos[3*s+2]-pos[3*t+2];
  float d = sqrtf(dx*dx+dy*dy+dz*dz+1e-12f);
  float acc[ECH];
  #pragma unroll
  for (int j=0;j<ECH;j++) acc[j]=b1l[j];
  if (d < CUTOFF_R){
    float env = 0.5f*(cosf(PI_F*(d/CUTOFF_R))+1.0f);
    int j0 = (int)floorf(d/SPACING);
    int klo = j0-9 > 0 ? j0-9 : 0;
    int khi = j0+10 < NBASIS-1 ? j0+10 : NBASIS-1;
    for (int k=klo;k<=khi;k++){
      float del = (d - k*SPACING)*INV_STD;
      float g = expf(-0.5f*del*del)*env;
      const float* wr = &w1[k*W1S];
      #pragma unroll
      for (int j=0;j<ECH;j++) acc[j] += g*wr[j];
    }
  }
  float e1[ECH];
  #pragma unroll
  for (int j=0;j<ECH;j++) e1[j] = silu_f(acc[j]);
  float* outp = e2g + (size_t)e*ECH;
  for (int j4=0;j4<ECH;j4+=4){
    float o[4];
    #pragma unroll
    for (int jj=0;jj<4;jj++){
      float a2 = b2l[j4+jj];
      #pragma unroll
      for (int k=0;k<ECH;k++) a2 += e1[k]*w2[k*ECH+j4+jj];
      o[jj] = silu_f(a2);
    }
    ((float4*)(outp+j4))[0] = make_float4(o[0],o[1],o[2],o[3]);
  }
}

// ---------- CSR build ----------
__global__ void k_hist(const int* __restrict__ ei, int* __restrict__ deg){
  int e = blockIdx.x*256 + threadIdx.x;
  atomicAdd(&deg[ei[EE+e]], 1);
}

__global__ void __launch_bounds__(1024) k_scan(const int* __restrict__ deg, int* __restrict__ off){
  __shared__ int sums[1024];
  int t = threadIdx.x;
  int base = t*8;
  int loc[8]; int s=0;
  #pragma unroll
  for (int i=0;i<8;i++){ int idx=base+i; int v = (idx<NN)? deg[idx]:0; loc[i]=v; s+=v; }
  sums[t]=s;
  __syncthreads();
  for (int d=1; d<1024; d<<=1){
    int v = (t>=d)? sums[t-d]:0;
    __syncthreads();
    sums[t] += v;
    __syncthreads();
  }
  int run = sums[t]-s;
  #pragma unroll
  for (int i=0;i<8;i++){ int idx=base+i; if (idx<NN) off[idx]=run; run+=loc[i]; }
  if (t==1023) off[NN]=sums[1023];
}

__global__ void k_fill(const int* __restrict__ ei, const int* __restrict__ off,
                       int* __restrict__ cursor, int* __restrict__ csr){
  int e = blockIdx.x*256 + threadIdx.x;
  int d = ei[EE+e];
  int slot = off[d] + atomicAdd(&cursor[d],1);
  csr[slot]=e;
}

// ---------- per-edge: e_c, s0, logits, v0 (grid 375x256) ----------
__global__ void __launch_bounds__(256) k_edgeB(const float* __restrict__ e2g, const int* __restrict__ ei,
                        const float* __restrict__ xs0, const float* __restrict__ xd0,
                        const float* __restrict__ W_edge, const float* __restrict__ W_alpha,
                        const float* __restrict__ v_alpha, const float* __restrict__ Wv,
                        float* __restrict__ logits_g, float* __restrict__ v0g){
  __shared__ float we[ECH*64];
  __shared__ float wv[4096];
  __shared__ float va[256];
  __shared__ float wab[64*68];   // transposed [j][k] chunk of W_alpha, padded stride 68
  for (int i=threadIdx.x;i<ECH*64;i+=256) we[i]=W_edge[i];
  for (int i=threadIdx.x;i<4096;i+=256) wv[i]=Wv[i];
  va[threadIdx.x]=v_alpha[threadIdx.x];
  __syncthreads();
  int e = blockIdx.x*256 + threadIdx.x;
  int s = ei[e], t = ei[EE+e];
  float e2r[ECH];
  {
    const float4* p = (const float4*)(e2g + (size_t)e*ECH);
    #pragma unroll
    for (int q=0;q<ECH/4;q++){
      float4 v4 = p[q];
      e2r[4*q+0]=v4.x; e2r[4*q+1]=v4.y; e2r[4*q+2]=v4.z; e2r[4*q+3]=v4.w;
    }
  }
  // s0 accumulates e_c first (static-index regs), then scaled by (xs0[src]+xd0[dst])
  float s0[64];
  #pragma unroll
  for (int c=0;c<64;c++) s0[c]=0.0f;
  for (int k=0;k<ECH;k++){
    float v = e2r[k];
    const float* wr = &we[k*64];
    #pragma unroll
    for (int c=0;c<64;c++) s0[c] += v*wr[c];
  }
  {
    const float4* ps = (const float4*)(xs0 + (size_t)s*64);
    const float4* pd = (const float4*)(xd0 + (size_t)t*64);
    #pragma unroll
    for (int q=0;q<16;q++){
      float4 a4 = ps[q]; float4 b4 = pd[q];
      s0[4*q+0] *= (a4.x+b4.x);
      s0[4*q+1] *= (a4.y+b4.y);
      s0[4*q+2] *= (a4.z+b4.z);
      s0[4*q+3] *= (a4.w+b4.w);
    }
  }
  // logits: per head, stage transposed W_alpha chunk, dot + leaky_relu + v_alpha
  float lg[HH];
  for (int h=0;h<HH;h++){
    __syncthreads();
    for (int i=threadIdx.x;i<4096;i+=256){
      int k = i>>6, j = i&63;                  // read coalesced (consecutive j)
      wab[j*68+k] = W_alpha[k*256 + h*64 + j]; // store transposed
    }
    __syncthreads();
    float acc = 0.0f;
    for (int j=0;j<64;j++){
      float tdot = 0.0f;
      const float* wc = &wab[j*68];
      #pragma unroll
      for (int k=0;k<64;k++) tdot += s0[k]*wc[k];
      acc += (tdot>0.0f ? tdot : 0.2f*tdot)*va[h*64+j];
    }
    lg[h]=acc;
  }
  ((float4*)(logits_g+(size_t)e*4))[0] = make_float4(lg[0],lg[1],lg[2],lg[3]);
  // v0 = s0 @ W_v
  float* vp = v0g + (size_t)e*64;
  for (int c=0;c<64;c+=4){
    float t0=0,t1=0,t2=0,t3=0;
    #pragma unroll
    for (int k=0;k<64;k++){
      float sv = s0[k];
      const float* wr = &wv[k*64+c];
      t0 += sv*wr[0]; t1 += sv*wr[1]; t2 += sv*wr[2]; t3 += sv*wr[3];
    }
    ((float4*)(vp+c))[0] = make_float4(t0,t1,t2,t3);
  }
}

// ---------- per-node softmax + aggregation + x1 = x + agg@W_o (grid NN x 256) ----------
__global__ void __launch_bounds__(256) k_agg(const int* __restrict__ off, const int* __restrict__ csr,
                       const int* __restrict__ ei,
                       const float* __restrict__ logits_g, const float* __restrict__ v0g,
                       const float* __restrict__ vs, const float* __restrict__ vd,
                       const float* __restrict__ x, const float* __restrict__ Wo,
                       float* __restrict__ out){
  __shared__ float aggl[1024];
  __shared__ float alph[MAXDEG*HH];
  __shared__ int   eidl[MAXDEG];
  __shared__ int   srcl[MAXDEG];
  __shared__ float salpha[HH];
  int n = blockIdx.x;
  int o0 = off[n];
  int deg = off[n+1]-o0;
  if (deg > MAXDEG) deg = MAXDEG;
  if ((int)threadIdx.x < deg){
    int e = csr[o0+threadIdx.x];
    eidl[threadIdx.x]=e;
    srcl[threadIdx.x]=ei[e];
    #pragma unroll
    for (int h=0;h<HH;h++) alph[threadIdx.x*HH+h]=logits_g[(size_t)e*HH+h];
  }
  __syncthreads();
  if (threadIdx.x < HH){
    int h = threadIdx.x;
    float m = -1e30f;
    for (int i=0;i<deg;i++) m = fmaxf(m, alph[i*HH+h]);
    float ds = 0.0f;
    for (int i=0;i<deg;i++){ float w = expf(alph[i*HH+h]-m); alph[i*HH+h]=w; ds += w; }
    float inv = 1.0f/(ds+1e-9f);
    for (int i=0;i<deg;i++) alph[i*HH+h] *= inv;
    salpha[h] = ds*inv;
  }
  __syncthreads();
  int c = threadIdx.x & 63;
  int wg = threadIdx.x >> 6;
  int h = c >> 4;
  for (int lp=wg; lp<16; lp+=4){
    float acc = 0.0f;
    if (lp==0){
      for (int i=0;i<deg;i++) acc += alph[i*HH+h]*v0g[(size_t)eidl[i]*64+c];
    } else {
      for (int i=0;i<deg;i++) acc += alph[i*HH+h]*vs[(size_t)srcl[i]*1024 + lp*64 + c];
      acc += salpha[h]*vd[(size_t)n*1024 + lp*64 + c];
    }
    aggl[lp*64+c]=acc;
  }
  __syncthreads();
  for (int idx=threadIdx.x; idx<1024; idx+=256){
    int l = idx>>6, cc = idx&63;
    float acc = x[(size_t)n*1024+idx];
    const float* ar = &aggl[l*64];
    #pragma unroll 8
    for (int k=0;k<64;k++) acc += ar[k]*Wo[k*64+cc];
    out[(size_t)n*1024+idx]=acc;
  }
}

// ---------- FFN: y=rmsnorm(x1); g=silu(y0@Wg); out = x1 + ((y@Wh)*g)@Wf (grid NN x 256) ----------
__global__ void __launch_bounds__(256) k_ffn(const float* __restrict__ x1,
                       const float* __restrict__ Wg, const float* __restrict__ Wh,
                       const float* __restrict__ Wf, float* __restrict__ out){
  __shared__ float xl[1024];
  __shared__ float yl[16*65];
  __shared__ float hl[16*FFNH];
  __shared__ float gl[FFNH];
  __shared__ float red[4];
  int n = blockIdx.x;
  float4 v = ((const float4*)(x1 + (size_t)n*1024))[threadIdx.x];
  ((float4*)xl)[threadIdx.x] = v;
  float ss = v.x*v.x+v.y*v.y+v.z*v.z+v.w*v.w;
  #pragma unroll
  for (int m=32;m>=1;m>>=1) ss += __shfl_xor(ss, m);
  if ((threadIdx.x & 63)==0) red[threadIdx.x>>6]=ss;
  __syncthreads();
  float scale = 1.0f/sqrtf((red[0]+red[1]+red[2]+red[3])*(1.0f/1024.0f)+1e-6f);
  for (int i=threadIdx.x;i<1024;i+=256) yl[(i>>6)*65+(i&63)] = xl[i]*scale;
  __syncthreads();
  if (threadIdx.x < FFNH){
    float a = 0.0f;
    #pragma unroll 8
    for (int k=0;k<64;k++) a += yl[k]*Wg[k*FFNH+threadIdx.x];
    gl[threadIdx.x] = silu_f(a);
  }
  __syncthreads();
  {
    int l = threadIdx.x>>4, cg = threadIdx.x&15;
    float acc[8];
    #pragma unroll
    for (int j=0;j<8;j++) acc[j]=0.0f;
    for (int k=0;k<64;k++){
      float a = yl[l*65+k];
      const float* wr = &Wh[k*FFNH + cg*8];
      #pragma unroll
      for (int j=0;j<8;j++) acc[j] += a*wr[j];
    }
    #pragma unroll
    for (int j=0;j<8;j++) hl[l*FFNH+cg*8+j] = acc[j]*gl[cg*8+j];
  }
  __syncthreads();
  for (int idx=threadIdx.x; idx<1024; idx+=256){
    int l = idx>>6, cc = idx&63;
    float acc = xl[idx];
    const float* hr = &hl[l*FFNH];
    #pragma unroll 8
    for (int k=0;k<FFNH;k++) acc += hr[k]*Wf[k*64+cc];
    out[(size_t)n*1024+idx]=acc;
  }
}

extern "C" void kernel_launch(void* const* d_in, const int* in_sizes, int n_in,
                              void* d_out, int out_size, void* d_ws, size_t ws_size,
                              hipStream_t stream) {
  (void)in_sizes; (void)n_in; (void)out_size; (void)ws_size;
  const float* pos = (const float*)d_in[0];
  const float* x   = (const float*)d_in[1];
  const float* Wsrc= (const float*)d_in[2];
  const float* Wdst= (const float*)d_in[3];
  const float* W1  = (const float*)d_in[4];
  const float* b1  = (const float*)d_in[5];
  const float* W2  = (const float*)d_in[6];
  const float* b2  = (const float*)d_in[7];
  const float* We  = (const float*)d_in[8];
  const float* Wa  = (const float*)d_in[9];
  const float* va  = (const float*)d_in[10];
  const float* Wv  = (const float*)d_in[11];
  const float* Wo  = (const float*)d_in[12];
  const float* Wg  = (const float*)d_in[13];
  const float* Wh  = (const float*)d_in[14];
  const float* Wf  = (const float*)d_in[15];
  const int*   ei  = (const int*)d_in[16];
  float* out = (float*)d_out;

  char* wp = (char*)d_ws;
  auto alloc = [&](size_t elems)->char*{
    char* p = wp;
    wp += ((elems*4 + 255)/256)*256;
    return p;
  };
  float* rms1 = (float*)alloc(NN);
  float* wsv  = (float*)alloc(4096);
  float* wdv  = (float*)alloc(4096);
  float* xs0  = (float*)alloc((size_t)NN*64);
  float* xd0  = (float*)alloc((size_t)NN*64);
  float* vs   = (float*)alloc((size_t)NN*1024);
  float* vd   = (float*)alloc((size_t)NN*1024);
  float* e2g  = (float*)alloc((size_t)EE*ECH);
  float* v0g  = (float*)alloc((size_t)EE*64);
  float* lgts = (float*)alloc((size_t)EE*HH);
  int* deg    = (int*)alloc(NN);
  int* cursor = (int*)alloc(NN);
  int* off    = (int*)alloc(NN+1);
  int* csr    = (int*)alloc(EE);

  hipMemsetAsync(deg, 0, NN*sizeof(int), stream);
  hipMemsetAsync(cursor, 0, NN*sizeof(int), stream);

  k_fusew<<<32,256,0,stream>>>(Wsrc,Wdst,Wv,wsv,wdv);
  k_rms<<<NN,256,0,stream>>>(x,rms1);
  k_node0<<<NN*64/256,256,0,stream>>>(x,rms1,Wsrc,Wdst,xs0,xd0);
  k_node1<<<NN*16/64,256,0,stream>>>(x,rms1,wsv,wdv,vs,vd);
  k_edgeA<<<EE/256,256,0,stream>>>(pos,ei,W1,b1,W2,b2,e2g);
  k_hist<<<EE/256,256,0,stream>>>(ei,deg);
  k_scan<<<1,1024,0,stream>>>(deg,off);
  k_fill<<<EE/256,256,0,stream>>>(ei,off,cursor,csr);
  k_edgeB<<<EE/256,256,0,stream>>>(e2g,ei,xs0,xd0,We,Wa,va,Wv,lgts,v0g);
  k_agg<<<NN,256,0,stream>>>(off,csr,ei,lgts,v0g,vs,vd,x,Wo,out);
  k_ffn<<<NN,256,0,stream>>>(out,Wg,Wh,Wf,out);
}